// Round 3
// baseline (91.579 us; speedup 1.0000x reference)
//
#include <hip/hip_runtime.h>
#include <math.h>

// B=64, C=256, HW=256, HEADS=8, HEAD_DIM=256, HID=2048, TEMB=512
// Identity: einsum 'bhnm,bhcl->bhml' contracts n,c independently =>
// softmaxes sum to 1 => q,k irrelevant; pre-projection output is
// SC^2 * colsum of v, constant over spatial l. Single cooperative-style
// kernel (manual grid barrier) to kill per-launch overhead (~10us x 5).

static constexpr float EPSV = 1e-6f;
static constexpr float SC2 = 1.0f / 256.0f;   // SC^2, SC = 256^-0.5

#define NBLK 256
#define NTHR 512

// Manual grid barrier. Safe: 256 blocks x 512 thr always co-resident
// (<= 1 block/CU at worst-case VGPR on 256 CUs). Agent-scope atomics
// give cross-XCD visibility (release on arrive, acquire on depart).
__device__ __forceinline__ void grid_sync(unsigned* cnt, unsigned* gen) {
    __syncthreads();
    if (threadIdx.x == 0) {
        unsigned g = __hip_atomic_load(gen, __ATOMIC_RELAXED,
                                       __HIP_MEMORY_SCOPE_AGENT);
        unsigned prev = __hip_atomic_fetch_add(cnt, 1u, __ATOMIC_ACQ_REL,
                                               __HIP_MEMORY_SCOPE_AGENT);
        if (prev == NBLK - 1) {
            __hip_atomic_store(cnt, 0u, __ATOMIC_RELAXED,
                               __HIP_MEMORY_SCOPE_AGENT);
            __hip_atomic_store(gen, g + 1u, __ATOMIC_RELEASE,
                               __HIP_MEMORY_SCOPE_AGENT);
        } else {
            while (__hip_atomic_load(gen, __ATOMIC_RELAXED,
                                     __HIP_MEMORY_SCOPE_AGENT) == g)
                __builtin_amdgcn_s_sleep(1);
            (void)__hip_atomic_load(gen, __ATOMIC_ACQUIRE,
                                    __HIP_MEMORY_SCOPE_AGENT);
        }
    }
    __syncthreads();
}

__global__ void __launch_bounds__(NTHR) k_fused(
    const float* __restrict__ x, const float* __restrict__ temb,
    const float* __restrict__ mlp_w, const float* __restrict__ mlp_b,
    const float* __restrict__ qkv_w, const float* __restrict__ out_w,
    const float* __restrict__ out_b, const float* __restrict__ onorm,
    float* __restrict__ out, float* __restrict__ ws)
{
    __shared__ float smem[8192];                   // 32 KB, reused per phase
    unsigned* cnt = (unsigned*)ws;
    unsigned* gen = ((unsigned*)ws) + 1;
    float* scsh = ws + 1024;     // [64 b][512 j]
    float* wvp  = ws + 34816;    // [64 chunk][256 ci]
    float* wt   = ws + 52224;    // [2048 o][256 c]  (out_w transposed)
    float* part = ws + 577536;   // [4 q][64 b][256 c]

    const int blk = blockIdx.x, tid = threadIdx.x;

    // ---------------- P1: weights prep + time-MLP --------------------
    if (blk < 64) {
        // scsh[b, j] = silu(temb[b]) . mlp_w[j] + mlp_b[j];  b = blk
        int b = blk;
        float v = temb[b * 512 + tid];
        smem[tid] = v / (1.0f + expf(-v));
        __syncthreads();
        const float4* wr =
            reinterpret_cast<const float4*>(mlp_w + (size_t)tid * 512);
        const float4* sl = reinterpret_cast<const float4*>(smem);
        float a0 = 0.f, a1 = 0.f, a2 = 0.f, a3 = 0.f;
        for (int t4 = 0; t4 < 128; t4 += 2) {
            float4 w0 = wr[t4], w1 = wr[t4 + 1];
            float4 s0 = sl[t4], s1 = sl[t4 + 1];
            a0 = fmaf(w0.x, s0.x, a0); a1 = fmaf(w0.y, s0.y, a1);
            a2 = fmaf(w0.z, s0.z, a2); a3 = fmaf(w0.w, s0.w, a3);
            a0 = fmaf(w1.x, s1.x, a0); a1 = fmaf(w1.y, s1.y, a1);
            a2 = fmaf(w1.z, s1.z, a2); a3 = fmaf(w1.w, s1.w, a3);
        }
        scsh[b * 512 + tid] = (a0 + a1) + (a2 + a3) + mlp_b[tid];
    } else if (blk < 128) {
        // wvp[w, ci]: 32-row partial column-sum of qkv_w's v-block
        int w = blk - 64;
        int ci = tid & 255, half = tid >> 8;
        const float* base =
            qkv_w + (size_t)(4096 + w * 32 + half * 16) * 256 + ci;
        float s = 0.f;
#pragma unroll
        for (int r = 0; r < 16; ++r) s += base[(size_t)r * 256];
        smem[half * 256 + ci] = s;
        __syncthreads();
        if (tid < 256) wvp[w * 256 + tid] = smem[tid] + smem[256 + tid];
    } else {
        // wt[o][c] = out_w[c][o], 64x64 tiles
        int t = blk - 128;                 // 0..127
        int ot = t >> 2, ct = t & 3;
        int col = tid & 63, rr = tid >> 6;
        float* tile = smem;                // [64][65]
#pragma unroll
        for (int r = 0; r < 8; ++r) {
            int row = r * 8 + rr;
            tile[row * 65 + col] =
                out_w[(size_t)(ct * 64 + row) * 2048 + ot * 64 + col];
        }
        __syncthreads();
#pragma unroll
        for (int r = 0; r < 8; ++r) {
            int row = r * 8 + rr;
            wt[(size_t)(ot * 64 + row) * 256 + ct * 64 + col] =
                tile[col * 65 + row];
        }
    }

    grid_sync(cnt, gen);

    // ---------------- P2: x-pass + partial out-projection ------------
    {
        int q = blk & 3, b = blk >> 2;     // q=blk&3 => one wt slice per XCD
        float* coef  = smem;               // [256 c][8 h]      2048
        float* red   = smem + 2048;        // [8 w][16 mt][36]  4608
        float* ofl   = smem + 6656;        // [512 o-local]
        float* ypart = smem + 7168;        // [2][256]
        float* ssh   = smem + 7680;        // [8]
        float* parts = smem + 7688;        // [4][8]

        if (tid < 256) {
            int c = tid;
            float sc = 1.0f + scsh[b * 512 + c];
            float sh = scsh[b * 512 + 256 + c];
#pragma unroll
            for (int h = 0; h < 8; ++h) {
                float wv = 0.f;
#pragma unroll
                for (int k = 0; k < 8; ++k) wv += wvp[(h * 8 + k) * 256 + c];
                coef[c * 8 + h] = sc * wv;
                float sv = sh * wv;
                sv += __shfl_xor(sv, 1);  sv += __shfl_xor(sv, 2);
                sv += __shfl_xor(sv, 4);  sv += __shfl_xor(sv, 8);
                sv += __shfl_xor(sv, 16); sv += __shfl_xor(sv, 32);
                if ((tid & 63) == 0) parts[(tid >> 6) * 8 + h] = sv;
            }
        }
        __syncthreads();
        if (tid < 8)
            ssh[tid] = parts[tid] + parts[8 + tid] +
                       parts[16 + tid] + parts[24 + tid];

        // x pass: acc[h*4+mi] = A, acc[32+mi] = ss2
        int mt = tid & 15, cg = tid >> 4;  // cg 0..31, 8 c each
        float acc[36];
#pragma unroll
        for (int i = 0; i < 36; ++i) acc[i] = 0.f;
        const float4* x4 = reinterpret_cast<const float4*>(x) +
                           (size_t)b * 16384 + q * 16 + mt;
#pragma unroll
        for (int ci = 0; ci < 8; ++ci) {
            int c = cg * 8 + ci;
            float4 xv = x4[(size_t)c * 64];
            float xa[4] = {xv.x, xv.y, xv.z, xv.w};
            const float4 cf0 = *reinterpret_cast<const float4*>(&coef[c * 8]);
            const float4 cf1 =
                *reinterpret_cast<const float4*>(&coef[c * 8 + 4]);
            float cf[8] = {cf0.x, cf0.y, cf0.z, cf0.w,
                           cf1.x, cf1.y, cf1.z, cf1.w};
#pragma unroll
            for (int h = 0; h < 8; ++h)
#pragma unroll
                for (int mi = 0; mi < 4; ++mi)
                    acc[h * 4 + mi] = fmaf(xa[mi], cf[h], acc[h * 4 + mi]);
#pragma unroll
            for (int mi = 0; mi < 4; ++mi)
                acc[32 + mi] = fmaf(xa[mi], xa[mi], acc[32 + mi]);
        }
#pragma unroll
        for (int i = 0; i < 36; ++i) {
            acc[i] += __shfl_xor(acc[i], 16);
            acc[i] += __shfl_xor(acc[i], 32);
        }
        int wv_ = tid >> 6, lane = tid & 63;
        if (lane < 16) {
#pragma unroll
            for (int i = 0; i < 36; ++i)
                red[(wv_ * 16 + lane) * 36 + i] = acc[i];
        }
        __syncthreads();
        if (tid < 16) {
            float fin[36];
#pragma unroll
            for (int i = 0; i < 36; ++i) {
                float s = 0.f;
#pragma unroll
                for (int w = 0; w < 8; ++w) s += red[(w * 16 + tid) * 36 + i];
                fin[i] = s;
            }
#pragma unroll
            for (int mi = 0; mi < 4; ++mi) {
                float inv = rsqrtf(fin[32 + mi] * (1.0f / 256.0f) + EPSV);
#pragma unroll
                for (int h = 0; h < 8; ++h)
                    ofl[h * 64 + tid * 4 + mi] =
                        SC2 * fmaf(inv, fin[h * 4 + mi], ssh[h]);
            }
        }
        __syncthreads();

        // partial projection: ypart[c] = sum_{o in block's 512} ofl*wt[o][c]
        int c = tid & 255, oh = tid >> 8;
        float y0 = 0.f, y1 = 0.f, y2 = 0.f, y3 = 0.f;
#pragma unroll
        for (int h = oh * 4; h < oh * 4 + 4; ++h) {
            const float* wrow = wt + ((size_t)(h * 256 + q * 64)) * 256 + c;
            const float* op = ofl + h * 64;
            for (int m = 0; m < 64; m += 4) {
                y0 = fmaf(op[m + 0], wrow[(size_t)(m + 0) * 256], y0);
                y1 = fmaf(op[m + 1], wrow[(size_t)(m + 1) * 256], y1);
                y2 = fmaf(op[m + 2], wrow[(size_t)(m + 2) * 256], y2);
                y3 = fmaf(op[m + 3], wrow[(size_t)(m + 3) * 256], y3);
            }
        }
        ypart[oh * 256 + c] = (y0 + y1) + (y2 + y3);
        __syncthreads();
        if (tid < 256)
            part[(size_t)q * 16384 + b * 256 + tid] =
                ypart[tid] + ypart[256 + tid];
    }

    grid_sync(cnt, gen);

    // ---------------- P3: reduce + RMS + g, stream out = x + g -------
    {
        int q = blk & 3, b = blk >> 2;
        float* g = smem;                   // [256]
        float* wred = smem + 256;          // [4]
        if (tid < 256) {
            int c = tid;
            float yb = out_b[c] +
                       part[b * 256 + c] + part[16384 + b * 256 + c] +
                       part[32768 + b * 256 + c] + part[49152 + b * 256 + c];
            float v = yb * yb;
            v += __shfl_xor(v, 1);  v += __shfl_xor(v, 2);
            v += __shfl_xor(v, 4);  v += __shfl_xor(v, 8);
            v += __shfl_xor(v, 16); v += __shfl_xor(v, 32);
            if ((tid & 63) == 0) wred[tid >> 6] = v;
            g[c] = yb;
        }
        __syncthreads();
        float tot = wred[0] + wred[1] + wred[2] + wred[3];
        float inv2 = rsqrtf(tot * (1.0f / 256.0f) + EPSV);
        if (tid < 256) g[tid] = g[tid] * inv2 * onorm[tid];
        __syncthreads();

        const float4* xx = reinterpret_cast<const float4*>(x) +
                           (size_t)b * 16384 + q * 16;
        float4* oo = reinterpret_cast<float4*>(out) +
                     (size_t)b * 16384 + q * 16;
#pragma unroll
        for (int i = tid; i < 4096; i += 512) {
            int row = i >> 4, col = i & 15;
            float4 xv = xx[(size_t)row * 64 + col];
            float gg = g[row];
            oo[(size_t)row * 64 + col] =
                make_float4(xv.x + gg, xv.y + gg, xv.z + gg, xv.w + gg);
        }
    }
}

extern "C" void kernel_launch(void* const* d_in, const int* in_sizes, int n_in,
                              void* d_out, int out_size, void* d_ws, size_t ws_size,
                              hipStream_t stream) {
    const float* x     = (const float*)d_in[0];
    const float* temb  = (const float*)d_in[1];
    const float* mlp_w = (const float*)d_in[2];
    const float* mlp_b = (const float*)d_in[3];
    const float* qkv_w = (const float*)d_in[4];
    const float* out_w = (const float*)d_in[5];
    const float* out_b = (const float*)d_in[6];
    const float* onorm = (const float*)d_in[7];
    float* out = (float*)d_out;
    float* ws  = (float*)d_ws;

    // barrier counters must be zero at every call (ws is poisoned 0xAA)
    hipMemsetAsync(ws, 0, 64, stream);
    k_fused<<<NBLK, NTHR, 0, stream>>>(x, temb, mlp_w, mlp_b, qkv_w,
                                       out_w, out_b, onorm, out, ws);
}